// Round 6
// baseline (95.657 us; speedup 1.0000x reference)
//
#include <hip/hip_runtime.h>
#include <hip/hip_bf16.h>
#include <hip/hip_fp16.h>

#define BDIM    128   // batch size, fixed by problem
#define NGROUPS 4     // batch groups (32 batches each), one per XCD pair
#define GCOLS   32    // batch columns per group
#define ROWB    (GCOLS * 2)            // bytes per xTh row = 64
#define EBLK    2048  // edge-kernel blocks (divisible by 8)
#define RANKS   (EBLK / NGROUPS)       // blocks per group = 512
#define WPG     (RANKS * 4)            // waves per group = 2048
#define S1BLK   (NGROUPS * 8)          // stage-1 edge-reduce blocks = 32
#define HBLK2   8     // stage-1 h-reduce blocks
#define RPS     (RANKS / 8)            // ranks per stage-1 block = 64

// ---------------------------------------------------------------------------
// Kernel 1: transpose+convert x (B=128,N) f32 -> xTh[g][N][32] fp16 slices,
// FUSED with h-term partials: hp[block][b] = sum_{n in tile} x[b,n]*h[n].
// Slice g holds batches [32g,32g+32) -> 3.2MB, L2-resident per XCD pair.
// ---------------------------------------------------------------------------
__global__ __launch_bounds__(256) void transpose_h_kernel(
    const float* __restrict__ x, const float* __restrict__ h,
    __half* __restrict__ xTh, float* __restrict__ hp, int N) {
  __shared__ float tile[64][BDIM + 1];
  __shared__ float sh[64];
  __shared__ float red2[2][BDIM];
  const int tid = threadIdx.x;
  const int n0  = blockIdx.x * 64;

  // load: lane-within-64 walks n (coalesced), 4 b-rows at a time
  const int tn  = tid & 63;
  const int tb0 = tid >> 6;
  const int n   = n0 + tn;
  if (n < N) {
    for (int b = tb0; b < BDIM; b += 4) tile[tn][b] = x[(size_t)b * N + n];
  } else {
    for (int b = tb0; b < BDIM; b += 4) tile[tn][b] = 0.f;
  }
  if (tid < 64) sh[tid] = (n0 + tid < N) ? h[n0 + tid] : 0.f;
  __syncthreads();

  // h-term partial: thread (half, b) sums 32 n's (tile reads stride-1: no conflict)
  const int hb   = tid & 127;
  const int half = tid >> 7;
  float hacc = 0.f;
#pragma unroll
  for (int m = 0; m < 32; ++m) {
    const int nl = half * 32 + m;
    hacc += tile[nl][hb] * sh[nl];
  }
  red2[half][hb] = hacc;

  // transpose store: thread = (k, g2, c2); 16 lanes write 64B contiguous
  const int c2 = tid & 15;         // column pair within group
  const int g2 = (tid >> 4) & 3;   // group
  const int k  = tid >> 6;         // n sub-row 0..3
  for (int it = 0; it < 16; ++it) {
    const int nl = it * 4 + k;
    if (n0 + nl < N) {
      const float a = tile[nl][g2 * GCOLS + 2 * c2];
      const float b = tile[nl][g2 * GCOLS + 2 * c2 + 1];
      __half2* dst = (__half2*)(xTh + ((size_t)g2 * N + (n0 + nl)) * GCOLS + 2 * c2);
      *dst = __floats2half2_rn(a, b);
    }
  }
  __syncthreads();
  if (tid < BDIM) hp[(size_t)blockIdx.x * BDIM + tid] = red2[0][tid] + red2[1][tid];
}

// ---------------------------------------------------------------------------
// 8-column packed-fp16 product, mixed-precision f32 accumulate.
// ---------------------------------------------------------------------------
__device__ __forceinline__ void fma8(float* acc, int4 vi, int4 vj, float Jv) {
  const int wi[4] = {vi.x, vi.y, vi.z, vi.w};
  const int wj[4] = {vj.x, vj.y, vj.z, vj.w};
#pragma unroll
  for (int w = 0; w < 4; ++w) {
    const __half2 hi = __builtin_bit_cast(__half2, wi[w]);
    const __half2 hj = __builtin_bit_cast(__half2, wj[w]);
    const __half2 p  = __hmul2(hi, hj);
    acc[2 * w]     += __low2float(p)  * Jv;
    acc[2 * w + 1] += __high2float(p) * Jv;
  }
}

// ---------------------------------------------------------------------------
// Kernel 2: edge interactions — barrier-free main loop. Each wave owns a
// private contiguous edge range. 4 lanes per edge (16B fp16 gather per lane
// = 8 columns); index loads ei/ej/J hit one 64B line per 16-edge step (each
// 4-lane quad reads the same address). 32 edges per unrolled iteration ->
// ~10 VMEM in flight per wave, 8 waves/SIMD -> L1<->L2 port kept busy.
// Block -> (group, rank): group g=(blockIdx&7)>>1 -> XCD pair {2g,2g+1},
// 3.2MB slice stays L2-resident.
// ---------------------------------------------------------------------------
__global__ __launch_bounds__(256, 8) void edge_kernel(
    const __half* __restrict__ xTh, const float* __restrict__ J,
    const int* __restrict__ ei, const int* __restrict__ ej,
    float* __restrict__ partials, int E, int N, int edges_per_wave) {
  const int tid  = threadIdx.x;
  const int g    = (blockIdx.x & 7) >> 1;
  const int rank = (blockIdx.x >> 3) * 2 + (blockIdx.x & 1);
  const int wave = tid >> 6;
  const int lane = tid & 63;
  const int k    = lane >> 2;          // edge sub-index 0..15
  const char* xgl = (const char*)xTh + (size_t)g * N * ROWB + (lane & 3) * 16;

  const int ws = (rank * 4 + wave) * edges_per_wave;
  const int we = min(ws + edges_per_wave, E);

  float acc[8] = {0.f, 0.f, 0.f, 0.f, 0.f, 0.f, 0.f, 0.f};

  int e0 = (ws < E) ? ws : E;
  // main loop: 32 edges, branch-free, no barriers
  for (; e0 + 32 <= we; e0 += 32) {
    const int eA = e0 + k;
    const int eB = eA + 16;
    const int   iA = ei[eA];
    const int   jA = ej[eA];
    const float JA = J[eA];
    const int   iB = ei[eB];
    const int   jB = ej[eB];
    const float JB = J[eB];
    const int4 viA = *(const int4*)(xgl + (unsigned)iA * ROWB);
    const int4 vjA = *(const int4*)(xgl + (unsigned)jA * ROWB);
    const int4 viB = *(const int4*)(xgl + (unsigned)iB * ROWB);
    const int4 vjB = *(const int4*)(xgl + (unsigned)jB * ROWB);
    fma8(acc, viA, vjA, JA);
    fma8(acc, viB, vjB, JB);
  }
  // tail: 16-edge steps, clamped indices + masked J
  for (; e0 < we; e0 += 16) {
    const int e = e0 + k;
    int i = 0, j = 0;
    float Jv = 0.f;
    if (e < we) { i = ei[e]; j = ej[e]; Jv = J[e]; }
    const int4 vi = *(const int4*)(xgl + (unsigned)i * ROWB);
    const int4 vj = *(const int4*)(xgl + (unsigned)j * ROWB);
    fma8(acc, vi, vj, Jv);
  }

  // combine the 16 k-lanes sharing each column quarter (xor 4,8,16,32)
#pragma unroll
  for (int off = 4; off < 64; off <<= 1)
#pragma unroll
    for (int w = 0; w < 8; ++w) acc[w] += __shfl_xor(acc[w], off);

  __shared__ float red[4][GCOLS];
  if (lane < 4)
#pragma unroll
    for (int w = 0; w < 8; ++w) red[wave][(lane & 3) * 8 + w] = acc[w];
  __syncthreads();
  if (tid < GCOLS) {
    const float s = red[0][tid] + red[1][tid] + red[2][tid] + red[3][tid];
    partials[((size_t)g * RANKS + rank) * GCOLS + tid] = s;
  }
}

// ---------------------------------------------------------------------------
// Kernel 3: stage-1 reduce. Blocks [0,32): edge partials (g,s) sum 64 rank
// rows -> P2. Blocks [32,40): h partials, block s sums rows r%8==s -> hp2.
// ---------------------------------------------------------------------------
__global__ __launch_bounds__(256) void reduce1_kernel(
    const float* __restrict__ P, const float* __restrict__ hp,
    float* __restrict__ P2, float* __restrict__ hp2, int hrows) {
  __shared__ float red[8][GCOLS];
  __shared__ float redh[2][BDIM];
  if (blockIdx.x < S1BLK) {
    const int g  = blockIdx.x >> 3;
    const int s  = blockIdx.x & 7;
    const int rl = threadIdx.x >> 5;  // 0..7
    const int c  = threadIdx.x & 31;
    float acc = 0.f;
    for (int rr = rl; rr < RPS; rr += 8)
      acc += P[((size_t)g * RANKS + s * RPS + rr) * GCOLS + c];
    red[rl][c] = acc;
    __syncthreads();
    if (threadIdx.x < GCOLS) {
      float sum = 0.f;
      for (int r = 0; r < 8; ++r) sum += red[r][threadIdx.x];
      P2[(size_t)blockIdx.x * GCOLS + threadIdx.x] = sum;
    }
  } else {
    const int s  = blockIdx.x - S1BLK;   // 0..7
    const int b  = threadIdx.x & 127;
    const int rg = threadIdx.x >> 7;
    float acc = 0.f;
    for (int r = s + 8 * rg; r < hrows; r += 16)
      acc += hp[(size_t)r * BDIM + b];
    redh[rg][b] = acc;
    __syncthreads();
    if (threadIdx.x < BDIM)
      hp2[(size_t)s * BDIM + threadIdx.x] = redh[0][threadIdx.x] + redh[1][threadIdx.x];
  }
}

// ---------------------------------------------------------------------------
// Kernel 4: final: out[b] = sum_s hp2[s][b] + sum_s P2[(g*8+s)][c].
// ---------------------------------------------------------------------------
__global__ __launch_bounds__(128) void reduce2_kernel(
    const float* __restrict__ P2, const float* __restrict__ hp2,
    float* __restrict__ out) {
  const int b = threadIdx.x;
  const int g = b >> 5;
  const int c = b & 31;
  float acc = 0.f;
  for (int s = 0; s < 8; ++s) acc += hp2[(size_t)s * BDIM + b];
  for (int s = 0; s < 8; ++s) acc += P2[(size_t)(g * 8 + s) * GCOLS + c];
  out[b] = acc;
}

extern "C" void kernel_launch(void* const* d_in, const int* in_sizes, int n_in,
                              void* d_out, int out_size, void* d_ws, size_t ws_size,
                              hipStream_t stream) {
  const float* x  = (const float*)d_in[0];
  const float* h  = (const float*)d_in[1];
  const float* J  = (const float*)d_in[2];
  const int*   ei = (const int*)d_in[3];
  const int*   ej = (const int*)d_in[4];
  float* out = (float*)d_out;

  const int N = in_sizes[1];   // 50000
  const int E = in_sizes[2];   // 1600000

  const int tblocks = (N + 63) / 64;

  // ws layout: xTh (4*N*32 halves) | P (EBLK*32) | P2 (32*32) | hp (tblocks*128) | hp2 (8*128)
  __half* xTh = (__half*)d_ws;
  float* P   = (float*)(xTh + (size_t)NGROUPS * N * GCOLS);
  float* P2  = P   + (size_t)EBLK * GCOLS;
  float* hp  = P2  + (size_t)S1BLK * GCOLS;
  float* hp2 = hp  + (size_t)tblocks * BDIM;

  // 1) transpose + fp16 convert + h-term partials
  transpose_h_kernel<<<tblocks, 256, 0, stream>>>(x, h, xTh, hp, N);

  // 2) edge interactions (4 batch groups, XCD-affine, barrier-free waves)
  //    edges per wave, rounded to a multiple of 32 so most waves are tail-free
  const int epw = (((E + WPG - 1) / WPG) + 31) & ~31;
  edge_kernel<<<EBLK, 256, 0, stream>>>(xTh, J, ei, ej, P, E, N, epw);

  // 3) stage-1 reduce (edge partials + h partials)
  reduce1_kernel<<<S1BLK + HBLK2, 256, 0, stream>>>(P, hp, P2, hp2, tblocks);

  // 4) final deterministic reduce (overwrites d_out)
  reduce2_kernel<<<1, BDIM, 0, stream>>>(P2, hp2, out);
}